// Round 1
// baseline (70.580 us; speedup 1.0000x reference)
//
#include <hip/hip_runtime.h>
#include <hip/hip_bf16.h>

// Problem constants from the reference setup: B=64, T=1024, D=2, max_lag=256.
#define TT 1024
#define DD 2
#define MAXLAG 256
#define LAG_CHUNKS 8              // 32 lags per block, 8 lags per wave (4 waves/block)

// ---------------- Kernel 1: MSD table ----------------
// grid (B, LAG_CHUNKS), block 256. msd_out[b*MAXLAG + (lag-1)]
__global__ __launch_bounds__(256) void msd_kernel(const float* __restrict__ traj,
                                                  const int* __restrict__ lengths,
                                                  float* __restrict__ msd_out) {
    __shared__ float s[TT * DD];          // 8 KB
    const int b = blockIdx.x;
    const int c = blockIdx.y;

    // Stage trajectory row into LDS with float4 (512 vec4 loads / 256 threads = 2 each)
    const float4* t4 = (const float4*)(traj + (size_t)b * TT * DD);
    float4* s4 = (float4*)s;
    for (int i = threadIdx.x; i < TT * DD / 4; i += 256) s4[i] = t4[i];
    __syncthreads();

    const int L = lengths[b];
    const int wave = threadIdx.x >> 6;
    const int lane = threadIdx.x & 63;
    const float2* s2 = (const float2*)s;

    for (int j = 0; j < 8; ++j) {
        const int lag = c * 32 + wave * 8 + j + 1;      // 1..256
        const int count = L - lag;                       // valid positions p in [0,count)
        float acc = 0.f;
        for (int p = lane; p < count; p += 64) {
            float2 a = s2[p];
            float2 e = s2[p + lag];
            float dx = e.x - a.x;
            float dy = e.y - a.y;
            acc += dx * dx + dy * dy;
        }
        // wave64 butterfly reduce
        for (int off = 32; off; off >>= 1) acc += __shfl_down(acc, off, 64);
        if (lane == 0) {
            float cnt = (float)(count > 1 ? count : 1);
            msd_out[b * MAXLAG + lag - 1] = acc / cnt;
        }
    }
}

// ---------------- Kernel 2: per-trajectory fit residual ----------------
// grid B, block 256 (one thread per lag)
__global__ __launch_bounds__(256) void fit_kernel(const float* __restrict__ alpha_pred,
                                                  const int* __restrict__ lengths,
                                                  const float* __restrict__ msd,
                                                  float* __restrict__ per_traj) {
    const int b = blockIdx.x;
    const int t = threadIdx.x;           // 0..255
    const int lag = t + 1;
    const int L = lengths[b];
    const float mask = (L > lag) ? 1.f : 0.f;
    const float log_lag = logf((float)lag);
    const float m = msd[b * MAXLAG + t];
    const float log_msd = logf(m + 1e-8f);
    const float alpha = alpha_pred[b];
    const float resid = log_msd - alpha * log_lag;

    const int wave = t >> 6;
    const int lane = t & 63;
    __shared__ float sr[4], sm[4], ss[4];

    float r = resid * mask, mk = mask;
    for (int off = 32; off; off >>= 1) {
        r  += __shfl_down(r,  off, 64);
        mk += __shfl_down(mk, off, 64);
    }
    if (lane == 0) { sr[wave] = r; sm[wave] = mk; }
    __syncthreads();
    const float sumr = sr[0] + sr[1] + sr[2] + sr[3];
    const float summ = sm[0] + sm[1] + sm[2] + sm[3];
    const float denom = fmaxf(summ, 1.f);
    const float intercept = sumr / denom;

    float d = (intercept - resid);       // == alpha*log_lag + intercept - log_msd
    float se = d * d * mask;
    for (int off = 32; off; off >>= 1) se += __shfl_down(se, off, 64);
    if (lane == 0) ss[wave] = se;
    __syncthreads();
    if (t == 0) per_traj[b] = (ss[0] + ss[1] + ss[2] + ss[3]) / denom;
}

// ---------------- Kernel 3: mean over batch ----------------
// 1 block, 64 threads (B == 64)
__global__ void mean_kernel(const float* __restrict__ per_traj, float* __restrict__ out, int B) {
    float v = (threadIdx.x < B) ? per_traj[threadIdx.x] : 0.f;
    for (int off = 32; off; off >>= 1) v += __shfl_down(v, off, 64);
    if (threadIdx.x == 0) out[0] = v / (float)B;
}

extern "C" void kernel_launch(void* const* d_in, const int* in_sizes, int n_in,
                              void* d_out, int out_size, void* d_ws, size_t ws_size,
                              hipStream_t stream) {
    const float* alpha = (const float*)d_in[0];
    const float* traj  = (const float*)d_in[1];
    const int*   lens  = (const int*)d_in[2];
    float* out = (float*)d_out;

    const int B = in_sizes[0];           // 64

    float* msd      = (float*)d_ws;                       // B*MAXLAG floats = 64 KB
    float* per_traj = msd + (size_t)B * MAXLAG;           // B floats

    dim3 g1(B, LAG_CHUNKS);
    msd_kernel<<<g1, 256, 0, stream>>>(traj, lens, msd);
    fit_kernel<<<B, 256, 0, stream>>>(alpha, lens, msd, per_traj);
    mean_kernel<<<1, 64, 0, stream>>>(per_traj, out, B);
}

// Round 2
// 65.564 us; speedup vs baseline: 1.0765x; 1.0765x over previous
//
#include <hip/hip_runtime.h>
#include <hip/hip_bf16.h>

// Problem constants: B=64, T=1024, D=2, max_lag = T/4 = 256, P = T-1 = 1023.
#define TT 1024
#define DD 2
#define MAXLAG 256
#define PCHUNKS 8
#define PCHUNK 128            // 8 * 128 = 1024 >= P

// ---------------- Kernel 1: MSD partial sums ----------------
// grid (B, PCHUNKS), block 256 (thread t <-> lag t+1).
// partial[(b*PCHUNKS+pc)*MAXLAG + t] = sum over p in chunk of |x[p+lag]-x[p]|^2
// Thread-per-lag layout: s2[p] is wave-uniform (LDS broadcast, conflict-free),
// s2[p+lag] is lane-consecutive float2 (2-way bank aliasing = free).
// Loop runs only valid p (p < L-lag), so p+lag <= L-1 <= 1023: no clamp needed.
__global__ __launch_bounds__(256) void msd_partial_kernel(const float* __restrict__ traj,
                                                          const int* __restrict__ lengths,
                                                          float* __restrict__ partial,
                                                          float* __restrict__ finish_ws) {
    __shared__ float s[TT * DD];          // 8 KB
    const int b = blockIdx.x;
    const int pc = blockIdx.y;

    const float4* t4 = (const float4*)(traj + (size_t)b * TT * DD);
    float4* s4 = (float4*)s;
    for (int i = threadIdx.x; i < TT * DD / 4; i += 256) s4[i] = t4[i];

    // Zero the fused-finish accumulator+counter for this call (kernel 1
    // completes before kernel 2 launches in stream order).
    if (b == 0 && pc == 0 && threadIdx.x < 2) finish_ws[threadIdx.x] = 0.0f;
    __syncthreads();

    const int L = lengths[b];
    const int lag = threadIdx.x + 1;      // 1..256
    const int cnt = L - lag;              // valid p in [0, cnt)
    const int p0 = pc * PCHUNK;
    const int p1 = p0 + PCHUNK;
    const int pend = (cnt < p1) ? cnt : p1;

    const float2* s2 = (const float2*)s;
    float acc = 0.0f;
    #pragma unroll 4
    for (int p = p0; p < pend; ++p) {
        float2 a = s2[p];                 // wave-uniform -> broadcast
        float2 e = s2[p + lag];           // lane-consecutive float2
        float dx = e.x - a.x;
        float dy = e.y - a.y;
        acc += dx * dx + dy * dy;
    }
    partial[((size_t)b * PCHUNKS + pc) * MAXLAG + threadIdx.x] = acc;
}

// ---------------- Kernel 2: fit + mean (fused, last-block finishes) ----------------
// grid B, block 256 (thread t <-> lag t+1).
__global__ __launch_bounds__(256) void fit_kernel(const float* __restrict__ alpha_pred,
                                                  const int* __restrict__ lengths,
                                                  const float* __restrict__ partial,
                                                  float* __restrict__ finish_ws,
                                                  float* __restrict__ out) {
    const int b = blockIdx.x;
    const int t = threadIdx.x;
    const int lag = t + 1;
    const int L = lengths[b];

    float acc = 0.0f;
    #pragma unroll
    for (int pc = 0; pc < PCHUNKS; ++pc)
        acc += partial[((size_t)b * PCHUNKS + pc) * MAXLAG + t];

    const float cntf = fmaxf((float)(L - lag), 1.0f);
    const float msd = acc / cntf;
    const float mask = (L > lag) ? 1.0f : 0.0f;
    const float resid = logf(msd + 1e-8f) - alpha_pred[b] * logf((float)lag);

    const int wave = t >> 6;
    const int lane = t & 63;
    __shared__ float sr[4], sm[4], ss[4];

    float r = resid * mask, mk = mask;
    for (int off = 32; off; off >>= 1) {
        r  += __shfl_down(r,  off, 64);
        mk += __shfl_down(mk, off, 64);
    }
    if (lane == 0) { sr[wave] = r; sm[wave] = mk; }
    __syncthreads();
    const float sumr  = sr[0] + sr[1] + sr[2] + sr[3];
    const float summ  = sm[0] + sm[1] + sm[2] + sm[3];
    const float denom = fmaxf(summ, 1.0f);
    const float intercept = sumr / denom;

    // sq_err = (alpha*log_lag + intercept - log_msd)^2 = (intercept - resid)^2
    float d = intercept - resid;
    float se = d * d * mask;
    for (int off = 32; off; off >>= 1) se += __shfl_down(se, off, 64);
    if (lane == 0) ss[wave] = se;
    __syncthreads();

    if (t == 0) {
        const float per_traj = (ss[0] + ss[1] + ss[2] + ss[3]) / denom;
        atomicAdd(&finish_ws[0], per_traj * (1.0f / 64.0f));   // B = 64
        __threadfence();
        unsigned old = atomicAdd((unsigned*)&finish_ws[1], 1u);
        if (old == gridDim.x - 1)
            out[0] = *((volatile float*)&finish_ws[0]);
    }
}

extern "C" void kernel_launch(void* const* d_in, const int* in_sizes, int n_in,
                              void* d_out, int out_size, void* d_ws, size_t ws_size,
                              hipStream_t stream) {
    const float* alpha = (const float*)d_in[0];
    const float* traj  = (const float*)d_in[1];
    const int*   lens  = (const int*)d_in[2];
    float* out = (float*)d_out;

    const int B = in_sizes[0];           // 64

    float* partial   = (float*)d_ws;                              // B*8*256 floats = 512 KB
    float* finish_ws = partial + (size_t)B * PCHUNKS * MAXLAG;    // [0]=acc, [1]=counter

    dim3 g1(B, PCHUNKS);
    msd_partial_kernel<<<g1, 256, 0, stream>>>(traj, lens, partial, finish_ws);
    fit_kernel<<<B, 256, 0, stream>>>(alpha, lens, partial, finish_ws, out);
}